// Round 3
// baseline (33.981 us; speedup 1.0000x reference)
//
#include <hip/hip_runtime.h>
#include <hip/hip_bf16.h>

// Chamfer min-matching loss, B=8, P=4096, D=2, fp32.
// d2(q,g) = |q|^2 + (|g|^2 - 2 q.g). Per base point precompute hx=-2gx,
// hy=-2gy, c=|g|^2 in LDS; inner loop: two chained v_pk_fma_f32 per
// (query, 2 base points) + v_min3 chain. sqrt deferred (monotone).
// QPT=8 queries/thread so 3 ds_read_b128 serve 32 pairs.

#define NB   8
#define NP   4096
#define QPT  8
#define QPB  (256 * QPT)      // 2048 queries per block
#define NPC  (NP / QPB)       // 2 query chunks

typedef float f32x2 __attribute__((ext_vector_type(2)));
typedef float f32x4 __attribute__((ext_vector_type(4)));

__device__ __forceinline__ f32x2 pk_fma(f32x2 a, f32x2 b, f32x2 c) {
    f32x2 d;
    asm("v_pk_fma_f32 %0, %1, %2, %3" : "=v"(d) : "v"(a), "v"(b), "v"(c));
    return d;
}

template <int NC>
__global__ __launch_bounds__(256) void chamferA(const float* __restrict__ pred,
                                                const float* __restrict__ gt,
                                                float* __restrict__ ws,
                                                float* __restrict__ out) {
    constexpr int CHUNK = NP / NC;
    __shared__ __align__(16) float shx[CHUNK];
    __shared__ __align__(16) float shy[CHUNK];
    __shared__ __align__(16) float sc[CHUNK];

    // zero the accumulator once; stream order puts this before chamferB.
    if (blockIdx.x == 0 && threadIdx.x == 0) *out = 0.0f;

    int bid = blockIdx.x;
    int gc  = bid % NC;  bid /= NC;
    int pc  = bid % NPC; bid /= NPC;
    int b   = bid % NB;  bid /= NB;
    int dir = bid;       // 0: query=pred base=gt ; 1: query=gt base=pred

    const float* query = dir ? gt : pred;
    const float* base  = dir ? pred : gt;

    const float2* base2 = (const float2*)base + (size_t)b * NP + gc * CHUNK;
    int t = threadIdx.x;

    for (int i = t; i < CHUNK; i += 256) {
        float2 g = base2[i];
        shx[i] = -2.0f * g.x;
        shy[i] = -2.0f * g.y;
        sc[i]  = g.x * g.x + g.y * g.y;
    }
    __syncthreads();

    const float2* query2 = (const float2*)query + (size_t)b * NP + pc * QPB;
    f32x2 px[QPT], py[QPT];
    float p2[QPT], m[QPT];
#pragma unroll
    for (int k = 0; k < QPT; ++k) {
        float2 q = query2[t + k * 256];
        px[k] = (f32x2){q.x, q.x};
        py[k] = (f32x2){q.y, q.y};
        p2[k] = q.x * q.x + q.y * q.y;
        m[k]  = 3.402823466e+38f;
    }

#pragma unroll 2
    for (int j = 0; j < CHUNK; j += 4) {
        f32x4 hx = *(const f32x4*)&shx[j];
        f32x4 hy = *(const f32x4*)&shy[j];
        f32x4 cc = *(const f32x4*)&sc[j];
        f32x2 hx01 = {hx.x, hx.y}, hx23 = {hx.z, hx.w};
        f32x2 hy01 = {hy.x, hy.y}, hy23 = {hy.z, hy.w};
        f32x2 c01  = {cc.x, cc.y}, c23  = {cc.z, cc.w};

#pragma unroll
        for (int k = 0; k < QPT; ++k) {
            f32x2 a, v;
            a = pk_fma(py[k], hy01, c01); a = pk_fma(px[k], hx01, a);
            v = pk_fma(py[k], hy23, c23); v = pk_fma(px[k], hx23, v);
            m[k] = fminf(fminf(m[k], a.x), a.y);   // v_min3_f32
            m[k] = fminf(fminf(m[k], v.x), v.y);
        }
    }

    size_t o = (((size_t)dir * NB + b) * NC + gc) * NP + pc * QPB + t;
#pragma unroll
    for (int k = 0; k < QPT; ++k) ws[o + k * 256] = m[k] + p2[k];
}

template <int NC>
__global__ __launch_bounds__(256) void chamferB(const float* __restrict__ ws,
                                                float* __restrict__ out) {
    int idx  = blockIdx.x * 256 + threadIdx.x;   // 0 .. 2*NB*NP-1
    int dirb = idx >> 12;                        // dir*NB + b
    int q    = idx & (NP - 1);

    const float* p = ws + ((size_t)dirb * NC) * NP + q;
    float mv = p[0];
#pragma unroll
    for (int c = 1; c < NC; ++c) mv = fminf(mv, p[(size_t)c * NP]);

    float v = sqrtf(fmaxf(mv, 1e-12f));

#pragma unroll
    for (int o = 32; o > 0; o >>= 1) v += __shfl_down(v, o, 64);

    __shared__ float wsum[4];
    int lane = threadIdx.x & 63;
    int w    = threadIdx.x >> 6;
    if (lane == 0) wsum[w] = v;
    __syncthreads();
    if (threadIdx.x == 0) {
        float sblk = wsum[0] + wsum[1] + wsum[2] + wsum[3];
        atomicAdd(out, sblk * (0.5f / (float)(NB * NP)));
    }
}

template <int NC>
static void launch(const float* pred, const float* gt, float* ws, float* out,
                   hipStream_t stream) {
    chamferA<NC><<<2 * NB * NPC * NC, 256, 0, stream>>>(pred, gt, ws, out);
    chamferB<NC><<<(2 * NB * NP) / 256, 256, 0, stream>>>(ws, out);
}

extern "C" void kernel_launch(void* const* d_in, const int* in_sizes, int n_in,
                              void* d_out, int out_size, void* d_ws, size_t ws_size,
                              hipStream_t stream) {
    const float* pred = (const float*)d_in[0];
    const float* gt   = (const float*)d_in[1];
    float*       out  = (float*)d_out;
    float*       wsf  = (float*)d_ws;

    (void)in_sizes; (void)n_in; (void)out_size;

    auto need = [](size_t nc) { return (size_t)2 * NB * nc * NP * sizeof(float); };

    if      (ws_size >= need(64)) launch<64>(pred, gt, wsf, out, stream);
    else if (ws_size >= need(32)) launch<32>(pred, gt, wsf, out, stream);
    else if (ws_size >= need(16)) launch<16>(pred, gt, wsf, out, stream);
    else if (ws_size >= need(4))  launch<4>(pred, gt, wsf, out, stream);
    else                          launch<1>(pred, gt, wsf, out, stream);
}